// Round 5
// baseline (127.143 us; speedup 1.0000x reference)
//
#include <hip/hip_runtime.h>
#include <hip/hip_bf16.h>

typedef __attribute__((ext_vector_type(8))) short short8;
typedef __attribute__((ext_vector_type(4))) float f32x4;
typedef unsigned short u16;
typedef unsigned int u32;

// B=512, M=40, H=128, D=64, C=128.
// Factored algebra: out[c,d] = sum_m x0[m,d] * T_m[c,d],
//   T_m[c,d] = sum_h W[c,h,m] * xk[h,d]   (pure bf16 GEMM, K=H=128)
// Telescoped (Abel): T accumulates over m, out += (s_m - s_{m+1}) * T_cum.
//
// R0-R4 lesson: every structure pinned at MfmaUtil ~35% while sustaining
// ~13.4 TB/s of L2 A-traffic (671 MB: each batch re-reads all of W3).
// At the MFMA floor the A-stream would need 39 TB/s > 34.5 TB/s L2
// ceiling -> L2-BW-bound. Fix: stage A in LDS once per block, amortize
// over NBAT=4 batches -> 164 MB total (~6.6 TB/s at target).
#define NB 512
#define NM 40
#define NH 128
#define ND 64
#define NC 128
#define KTOT 5120

__device__ __forceinline__ u16 f2bf_rne(float f) {
    u32 u = __float_as_uint(f);
    u32 r = u + 0x7FFFu + ((u >> 16) & 1u);
    return (u16)(r >> 16);
}

__device__ __forceinline__ void gload16(const void* g, void* l) {
    __builtin_amdgcn_global_load_lds(
        (const __attribute__((address_space(1))) void*)g,
        (__attribute__((address_space(3))) void*)l, 16, 0, 0);
}

// W fp32 [C][h*40+m] -> bf16 W3 granule layout: byte offset of 16B granule
// (m,t,q,c) = ((m*16 + t*4 + q)*128 + c)*16, holding W[c][h=t*32+q*8+j][m]
// for j=0..7. (Proven rounds 0-4.)
__global__ void w3_kernel(const float* __restrict__ W, u16* __restrict__ W3) {
    __shared__ u16 kbuf[NH * 20];          // [h][mo], m-half only
    const int c = blockIdx.x >> 1, mh = blockIdx.x & 1;
    const float* src = W + (size_t)c * KTOT + mh * 20;
    for (int i = threadIdx.x; i < NH * 5; i += 256) {   // i = h*5 + j4
        int h = i / 5, j4 = i % 5;
        float4 v = *(const float4*)(src + h * NM + j4 * 4);
        u16* kb = kbuf + h * 20 + j4 * 4;
        kb[0] = f2bf_rne(v.x); kb[1] = f2bf_rne(v.y);
        kb[2] = f2bf_rne(v.z); kb[3] = f2bf_rne(v.w);
    }
    __syncthreads();
    for (int i = threadIdx.x; i < 320; i += 256) {      // i = mo*16 + t*4 + q
        int mo = i >> 4, t = (i >> 2) & 3, q = i & 3;
        int n = (mh * 20 + mo) * 16 + t * 4 + q;
        union { short8 s8; u16 e[8]; } v;
#pragma unroll
        for (int j = 0; j < 8; ++j)
            v.e[j] = kbuf[(t * 32 + q * 8 + j) * 20 + mo];
        *(short8*)(W3 + ((size_t)n * 128 + c) * 8) = v.s8;
    }
}

// main: grid 256 = group(128 of 4 batches) x c-half(2), 512 thr = 8 waves
// = bn(4 batches) x mh(2 m-halves). Wave: 64 c x 64 d, m in [mh*20,+20).
// Per m-step the block stages BOTH m-half A-tiles (2 x 16 KB) into an LDS
// ring via global_load_lds; all 4 bn-waves of an mh read the same staged
// tile -> L2 A-traffic /4. Protocol = proven 2-phase: stage(next)->buf^1,
// compute buf, s_waitcnt vmcnt(0), __syncthreads(). B (xk) reg-cached per
// wave; telescoped x0 scaling; mh-pair reduce epilogue (R1-proven).
__global__ void __launch_bounds__(512, 2) cin_main(
    const float* __restrict__ x0g, const float* __restrict__ xkg,
    const float* __restrict__ biasg, const u16* __restrict__ W3,
    float* __restrict__ out)
{
    // Region A [0,69632): xkT bf16 [4][64][136] (prologue) -> overlay:
    //   A-ring 2 x 32768 (main loop) -> red f32 [4][64][68] (epilogue)
    // x0s f32 [4][40][68] @69632 | bias @113152 ; total 113664 B (1 blk/CU)
    __shared__ __align__(16) char smem[113664];
    short* xkT    = (short*)smem;
    char*  ring   = smem;
    float* red    = (float*)smem;
    float* x0s    = (float*)(smem + 69632);
    float* bias_s = (float*)(smem + 113152);

    const int tid = threadIdx.x;
    const int w = tid >> 6, L = tid & 63;
    const int q = L >> 4, l16 = L & 15;
    const int bn = w >> 1;                  // batch within group
    const int mh = w & 1;                   // m-half: [mh*20, mh*20+20)
    const int ch = blockIdx.x & 1;          // c-half
    const size_t b0 = 4 * (size_t)(blockIdx.x >> 1);
    const int m0 = mh * 20;

    // ---- staging map: granule j = e*512 + tid, j -> (mhs,t,q,c'):
    //   mhs=j>>10, jj=j&1023, t=jj>>8, q=(jj>>6)&3, c'=jj&63
    // src granule (m_abs = mhs*20 + lm, c = ch*64+c'):
    //   byte = ((m_abs*16 + t*4 + q)*128 + ch*64 + c')*16
    // dst byte (slot) = e*8192 + tid*16  (= j*16, wave-uniform base + L*16)
    const char* W3b = (const char*)W3;
    u32 srcOff[4];
#pragma unroll
    for (int e = 0; e < 4; ++e) {
        int j = e * 512 + tid;
        int mhs = j >> 10, jj = j & 1023;
        int tt = jj >> 8, qq = (jj >> 6) & 3, cc = jj & 63;
        srcOff[e] = (u32)(((tt * 4 + qq) * 128 + ch * 64 + cc) * 16)
                  + (u32)mhs * 20u * 32768u;
    }
    auto stageM = [&](int lm1, int slot) {   // stage both mh tiles for lm1
#pragma unroll
        for (int e = 0; e < 4; ++e)
            gload16(W3b + (size_t)(srcOff[e] + (u32)lm1 * 32768u),
                    ring + slot * 32768 + e * 8192 + tid * 16);
    };

    // ---- prologue: 4 batches xk -> bf16 xkT (transposed), x0 -> LDS, bias
    for (int i = tid; i < 8192; i += 512) {           // (bn, h, d4)
        int bi = i >> 11, rem = i & 2047;
        int h = rem >> 4, d4 = (rem & 15) << 2;
        float4 v = *(const float4*)(xkg + (b0 + bi) * (NH * ND) + h * ND + d4);
        short* xT = xkT + bi * 8704;
        xT[(d4 + 0) * 136 + h] = (short)f2bf_rne(v.x);
        xT[(d4 + 1) * 136 + h] = (short)f2bf_rne(v.y);
        xT[(d4 + 2) * 136 + h] = (short)f2bf_rne(v.z);
        xT[(d4 + 3) * 136 + h] = (short)f2bf_rne(v.w);
    }
    for (int i = tid; i < 2560; i += 512) {           // (bn, m, d4)
        int bi = i / 640, rem = i % 640;
        int m = rem >> 4, d4 = (rem & 15) << 2;
        *(f32x4*)(x0s + bi * 2720 + m * 68 + d4) =
            *(const f32x4*)(x0g + (b0 + bi) * (NM * ND) + m * ND + d4);
    }
    if (tid < NC) bias_s[tid] = biasg[tid];
    __syncthreads();

    // B frag register cache (from xkT before overlay):
    // bR[t][n] = xk[bn][h=t*32+q*8+j][d=n*16+l16]
    const short* Bp = xkT + bn * 8704 + (size_t)l16 * 136 + q * 8;
    short8 bR[4][4];
#pragma unroll
    for (int t = 0; t < 4; ++t)
#pragma unroll
        for (int n = 0; n < 4; ++n)
            bR[t][n] = *(const short8*)(Bp + n * (16 * 136) + t * 32);

    const float* x0p = x0s + bn * 2720;      // [40][68]
    float s[4], sn[4];
#pragma unroll
    for (int n = 0; n < 4; ++n)
        s[n] = x0p[m0 * 68 + n * 16 + l16];

    __syncthreads();                          // all xkT reads done -> overlay
    stageM(0, 0);                             // first tile into ring[0]
    asm volatile("s_waitcnt vmcnt(0)" ::: "memory");
    __syncthreads();

    f32x4 T[4][4] = {};      // cumulative GEMM acc (wave's 64c x 64d)
    f32x4 o[4][4] = {};      // scaled output acc

#pragma unroll 2
    for (int lm = 0; lm < 20; ++lm) {
        const int slot = lm & 1;
        if (lm < 19) stageM(lm + 1, slot ^ 1);   // L2 latency hides under 4 bodies
        const char* tb = ring + slot * 32768 + mh * 16384;
#pragma unroll
        for (int t = 0; t < 4; ++t) {
            short8 aR[4];
#pragma unroll
            for (int mt = 0; mt < 4; ++mt)
                aR[mt] = *(const short8*)(tb + t * 4096 + q * 1024 + (mt * 16 + l16) * 16);
            if (t == 0) {
#pragma unroll
                for (int n = 0; n < 4; ++n)
                    sn[n] = (lm < 19) ? x0p[(m0 + lm + 1) * 68 + n * 16 + l16] : 0.f;
            }
#pragma unroll
            for (int n = 0; n < 4; ++n) {
                T[0][n] = __builtin_amdgcn_mfma_f32_16x16x32_bf16(aR[0], bR[t][n], T[0][n], 0, 0, 0);
                T[1][n] = __builtin_amdgcn_mfma_f32_16x16x32_bf16(aR[1], bR[t][n], T[1][n], 0, 0, 0);
                T[2][n] = __builtin_amdgcn_mfma_f32_16x16x32_bf16(aR[2], bR[t][n], T[2][n], 0, 0, 0);
                T[3][n] = __builtin_amdgcn_mfma_f32_16x16x32_bf16(aR[3], bR[t][n], T[3][n], 0, 0, 0);
            }
            if (t == 3) {        // telescoped scale: out += (s_m - s_{m+1}) * T
#pragma unroll
                for (int n = 0; n < 4; ++n) {
                    const float dd = s[n] - sn[n];
#pragma unroll
                    for (int mt = 0; mt < 4; ++mt)
                        o[mt][n] += dd * T[mt][n];
                    s[n] = sn[n];
                }
            }
        }
        asm volatile("s_waitcnt vmcnt(0)" ::: "memory");
        __syncthreads();
    }

    // ---- epilogue: mh-pair reduce in LDS (R1-proven), overlay region A
    float* myred = red + bn * 4352;          // [64 d][68 c-stride]
    if (mh == 1) {
#pragma unroll
        for (int mt = 0; mt < 4; ++mt)
#pragma unroll
            for (int n = 0; n < 4; ++n) {
                int d = n * 16 + l16;
                *(f32x4*)(myred + d * 68 + mt * 16 + q * 4) = o[mt][n];
            }
    }
    __syncthreads();
    if (mh == 0) {
        float* op = out + (b0 + bn) * (NC * ND);
#pragma unroll
        for (int mt = 0; mt < 4; ++mt)
#pragma unroll
            for (int n = 0; n < 4; ++n) {
                int d = n * 16 + l16;
                f32x4 r = *(const f32x4*)(myred + d * 68 + mt * 16 + q * 4);
#pragma unroll
                for (int rr = 0; rr < 4; ++rr) {
                    int c = ch * 64 + mt * 16 + q * 4 + rr;
                    op[c * ND + d] = o[mt][n][rr] + r[rr] + bias_s[c];
                }
            }
    }
}

extern "C" void kernel_launch(void* const* d_in, const int* in_sizes, int n_in,
                              void* d_out, int out_size, void* d_ws, size_t ws_size,
                              hipStream_t stream) {
    const float* x0 = (const float*)d_in[0];
    const float* xk = (const float*)d_in[1];
    const float* W  = (const float*)d_in[2];
    const float* bi = (const float*)d_in[3];
    float* out = (float*)d_out;

    u16* W3 = (u16*)d_ws;                      // 655360 shorts = 1.31 MB

    w3_kernel<<<NC * 2, 256, 0, stream>>>(W, W3);
    cin_main<<<256, 512, 0, stream>>>(x0, xk, bi, W3, out);
}

// Round 6
// 126.160 us; speedup vs baseline: 1.0078x; 1.0078x over previous
//
#include <hip/hip_runtime.h>
#include <hip/hip_bf16.h>

typedef __attribute__((ext_vector_type(8))) short short8;
typedef __attribute__((ext_vector_type(4))) float f32x4;
typedef unsigned short u16;
typedef unsigned int u32;

// B=512, M=40, H=128, D=64, C=128.
// Factored algebra: out[c,d] = sum_m x0[m,d] * T_m[c,d],
//   T_m[c,d] = sum_h W[c,h,m] * xk[h,d]   (pure bf16 GEMM, K=H=128)
// Telescoped (Abel): T accumulates over m, out += (s_m - s_{m+1}) * T_cum.
// The telescope is LINEAR in T -> K can be split across waves (kh), each
// half accumulating its own o; one LDS reduce at the end.
//
// R5 falsified the L2-BW theory (4x less A-traffic -> slower). Diagnosis:
// latency-bound. Waves idle ~2400 cyc per m-group on vmcnt with only
// depth-2 prefetch slack; register wall (bR=64 at K=128) blocked both
// deeper rings and more waves. Fix: K-split halves bR+acc -> ~110 regs ->
// 4 waves/SIMD; A prefetch moved to per-wave PRIVATE LDS rings via
// global_load_lds (no VGPR cost, depth 4, counted vmcnt(3), NO barriers).
#define NB 512
#define NM 40
#define NH 128
#define ND 64
#define NC 128
#define KTOT 5120

__device__ __forceinline__ u16 f2bf_rne(float f) {
    u32 u = __float_as_uint(f);
    u32 r = u + 0x7FFFu + ((u >> 16) & 1u);
    return (u16)(r >> 16);
}

__device__ __forceinline__ void gload16(const void* g, void* l) {
    __builtin_amdgcn_global_load_lds(
        (const __attribute__((address_space(1))) void*)g,
        (__attribute__((address_space(3))) void*)l, 16, 0, 0);
}

// W fp32 [C][h*40+m] -> bf16 W3 granule layout: 16B granule (m,t,q,c) at
// byte ((m*16 + t*4 + q)*128 + c)*16, holding W[c][h=t*32+q*8+j][m], j=0..7.
// (Proven rounds 0-5.)
__global__ void w3_kernel(const float* __restrict__ W, u16* __restrict__ W3) {
    __shared__ u16 kbuf[NH * 20];          // [h][mo], m-half only
    const int c = blockIdx.x >> 1, mh = blockIdx.x & 1;
    const float* src = W + (size_t)c * KTOT + mh * 20;
    for (int i = threadIdx.x; i < NH * 5; i += 256) {   // i = h*5 + j4
        int h = i / 5, j4 = i % 5;
        float4 v = *(const float4*)(src + h * NM + j4 * 4);
        u16* kb = kbuf + h * 20 + j4 * 4;
        kb[0] = f2bf_rne(v.x); kb[1] = f2bf_rne(v.y);
        kb[2] = f2bf_rne(v.z); kb[3] = f2bf_rne(v.w);
    }
    __syncthreads();
    for (int i = threadIdx.x; i < 320; i += 256) {      // i = mo*16 + t*4 + q
        int mo = i >> 4, t = (i >> 2) & 3, q = i & 3;
        int n = (mh * 20 + mo) * 16 + t * 4 + q;
        union { short8 s8; u16 e[8]; } v;
#pragma unroll
        for (int j = 0; j < 8; ++j)
            v.e[j] = kbuf[(t * 32 + q * 8 + j) * 20 + mo];
        *(short8*)(W3 + ((size_t)n * 128 + c) * 8) = v.s8;
    }
}

// main: grid 1024 = batch(512) x c-half(2), 512 thr = 8 waves =
// rh(4 c-slices of 16) x kh(2 k-halves of 64). Wave: 16c x 64d x 64k.
// Body u = m*2 + th (80 bodies): 1 gload16 (wave's next A-granule, 1KB,
// per-lane gather src -> linear per-wave LDS ring slot), s_waitcnt
// vmcnt(3), 1 ds_read_b128 A-frag, 4 MFMAs, telescope at th==1.
// Ring depth 4 -> 3 bodies (~900+ cyc) of latency slack; rings are
// wave-private -> zero in-loop barriers. Epilogue: kh-pair LDS reduce.
__global__ void __launch_bounds__(512, 4) cin_main(
    const float* __restrict__ x0g, const float* __restrict__ xkg,
    const float* __restrict__ biasg, const u16* __restrict__ W3,
    float* __restrict__ out)
{
    // ring [8 waves][4 slots][1024B] = 32768 (epilogue overlay: red
    // [4 pairs][64 d][20 c-pad] f32 = 20480) | xkT bf16 [64][144] @32768
    // | x0s f32 [40][68] @51200 | bias @62080 ; total 62592 -> 2 blk/CU.
    __shared__ __align__(16) char smem[62592];
    char*  ring   = smem;
    float* red    = (float*)smem;
    short* xkT    = (short*)(smem + 32768);
    float* x0s    = (float*)(smem + 51200);
    float* bias_s = (float*)(smem + 62080);

    const int tid = threadIdx.x;
    const int w = tid >> 6, L = tid & 63;
    const int q = L >> 4, l16 = L & 15;
    const int kh = w & 1;                   // k-half: h in [kh*64, +64)
    const int rh = w >> 1;                  // c-slice: c = ch*64 + rh*16 + ..
    const int ch = blockIdx.x & 1;          // c-half
    const size_t b = blockIdx.x >> 1;       // batch

    // A-granule source for body u (m=u>>1, th=u&1), lane (q,l16):
    //   byte = (m*16 + (kh*2+th)*4 + q)*2048 + (ch*64 + rh*16 + l16)*16
    const char* A0 = (const char*)W3
        + (size_t)(kh * 16384 + q * 2048 + (ch * 64 + rh * 16 + l16) * 16);
    char* ringw = ring + w * 4096;          // wave-private 4-slot ring

    auto stage = [&](int ua, int slot) {    // ua = address body (clamped)
        gload16(A0 + (size_t)(ua >> 1) * 32768 + (size_t)(ua & 1) * 8192,
                ringw + slot * 1024 + L * 16);
    };
    // depth-4 ring: issue bodies 0..2 now; latency hides under prologue
    stage(0, 0); stage(1, 1); stage(2, 2);

    // ---- prologue: xk -> bf16 xkT (transposed, stride 144), x0 -> LDS
    for (int i = tid; i < 2048; i += 512) {           // (h, d4)
        int h = i >> 4, d4 = (i & 15) << 2;
        float4 v = *(const float4*)(xkg + b * (NH * ND) + h * ND + d4);
        xkT[(d4 + 0) * 144 + h] = (short)f2bf_rne(v.x);
        xkT[(d4 + 1) * 144 + h] = (short)f2bf_rne(v.y);
        xkT[(d4 + 2) * 144 + h] = (short)f2bf_rne(v.z);
        xkT[(d4 + 3) * 144 + h] = (short)f2bf_rne(v.w);
    }
    for (int i = tid; i < 640; i += 512) {            // (m, d4)
        int m = i >> 4, d4 = (i & 15) << 2;
        *(f32x4*)(x0s + m * 68 + d4) =
            *(const f32x4*)(x0g + b * (NM * ND) + m * ND + d4);
    }
    if (tid < NC) bias_s[tid] = biasg[tid];
    __syncthreads();

    // B frag register cache (half-K): bR[th][n] = xk[h=kh*64+th*32+q*8+j][d]
    const short* Bp = xkT + (size_t)l16 * 144 + kh * 64 + q * 8;
    short8 bR[2][4];
#pragma unroll
    for (int th = 0; th < 2; ++th)
#pragma unroll
        for (int n = 0; n < 4; ++n)
            bR[th][n] = *(const short8*)(Bp + n * (16 * 144) + th * 32);

    float s[4], sn[4];
#pragma unroll
    for (int n = 0; n < 4; ++n)
        s[n] = x0s[n * 16 + l16];            // m = 0

    f32x4 T[4] = {{0.f,0.f,0.f,0.f},{0.f,0.f,0.f,0.f},{0.f,0.f,0.f,0.f},{0.f,0.f,0.f,0.f}};
    f32x4 o[4] = {{0.f,0.f,0.f,0.f},{0.f,0.f,0.f,0.f},{0.f,0.f,0.f,0.f},{0.f,0.f,0.f,0.f}};

#pragma unroll 4
    for (int u = 0; u < 80; ++u) {           // u = m*2 + th
        const int th = u & 1;
        // issue body u+3's granule; tail re-issues granule 79 into the
        // just-freed slot (keeps exactly 1 issue/body -> vmcnt count exact)
        const int un = u + 3;
        stage((un < 80) ? un : 79, un & 3);
        // wait: oldest outstanding (body u's granule) complete; u+1..u+3
        // stay in flight. One gload per body -> vmcnt(3) is exact.
        asm volatile("s_waitcnt vmcnt(3)" ::: "memory");
        const short8 a = *(const short8*)(ringw + (u & 3) * 1024 + L * 16);
        if (th == 0) {
            const int m = u >> 1;
#pragma unroll
            for (int n = 0; n < 4; ++n)
                sn[n] = (m < 39) ? x0s[(m + 1) * 68 + n * 16 + l16] : 0.f;
        }
        T[0] = __builtin_amdgcn_mfma_f32_16x16x32_bf16(a, bR[th][0], T[0], 0, 0, 0);
        T[1] = __builtin_amdgcn_mfma_f32_16x16x32_bf16(a, bR[th][1], T[1], 0, 0, 0);
        T[2] = __builtin_amdgcn_mfma_f32_16x16x32_bf16(a, bR[th][2], T[2], 0, 0, 0);
        T[3] = __builtin_amdgcn_mfma_f32_16x16x32_bf16(a, bR[th][3], T[3], 0, 0, 0);
        if (th == 1) {       // telescoped scale: out += (s_m - s_{m+1}) * T
#pragma unroll
            for (int n = 0; n < 4; ++n) {
                const float dd = s[n] - sn[n];
                o[n] += dd * T[n];
                s[n] = sn[n];
            }
        }
    }

    // drain stray tail gloads before overlaying the ring with red
    asm volatile("s_waitcnt vmcnt(0)" ::: "memory");
    __syncthreads();

    // ---- epilogue: kh-pair reduce in LDS, pair = rh; red [64 d][20 c-pad]
    float* myred = red + rh * 1280;
    if (kh == 1) {
#pragma unroll
        for (int n = 0; n < 4; ++n) {
            int d = n * 16 + l16;
            *(f32x4*)(myred + d * 20 + q * 4) = o[n];
        }
    }
    __syncthreads();
    if (kh == 0) {
        float* op = out + b * (NC * ND);
#pragma unroll
        for (int n = 0; n < 4; ++n) {
            int d = n * 16 + l16;
            f32x4 r = *(const f32x4*)(myred + d * 20 + q * 4);
#pragma unroll
            for (int rr = 0; rr < 4; ++rr) {
                int c = ch * 64 + rh * 16 + q * 4 + rr;
                op[c * ND + d] = o[n][rr] + r[rr] + bias_s[c];
            }
        }
    }
}

extern "C" void kernel_launch(void* const* d_in, const int* in_sizes, int n_in,
                              void* d_out, int out_size, void* d_ws, size_t ws_size,
                              hipStream_t stream) {
    const float* x0 = (const float*)d_in[0];
    const float* xk = (const float*)d_in[1];
    const float* W  = (const float*)d_in[2];
    const float* bi = (const float*)d_in[3];
    float* out = (float*)d_out;

    u16* W3 = (u16*)d_ws;                      // 655360 shorts = 1.31 MB

    w3_kernel<<<NC * 2, 256, 0, stream>>>(W, W3);
    cin_main<<<NB * 2, 512, 0, stream>>>(x0, xk, bi, W3, out);
}